// Round 10
// baseline (442.684 us; speedup 1.0000x reference)
//
#include <hip/hip_runtime.h>
#include <hip/hip_bf16.h>
#include <stdint.h>

#define EMB 768
#define HEADS 12
#define BATCH 8
#define SEQ 1024
#define HD 64
#define M_ROWS (BATCH * SEQ)   /* 8192 */
#define QKV_COLS (3 * EMB)     /* 2304 */

typedef __attribute__((ext_vector_type(8))) short short8;
typedef __attribute__((ext_vector_type(4))) float f32x4;

__device__ __forceinline__ unsigned short f2bf(float x) {
    union { float f; unsigned u; } v; v.f = x;
    unsigned r = v.u + 0x7FFFu + ((v.u >> 16) & 1u);
    return (unsigned short)(r >> 16);
}
__device__ __forceinline__ float bf2f(unsigned short h) {
    union { unsigned u; float f; } v; v.u = ((unsigned)h) << 16;
    return v.f;
}
__device__ __forceinline__ float truncbf(float x) {
    return __uint_as_float(__float_as_uint(x) & 0xFFFF0000u);
}
__device__ __forceinline__ uint32_t packtr(float a, float b) {   // lo16=tr(a), hi16=tr(b)
    return (__float_as_uint(a) >> 16) | (__float_as_uint(b) & 0xFFFF0000u);
}

#define MFMA16(a, b, c) __builtin_amdgcn_mfma_f32_16x16x32_bf16((a), (b), (c), 0, 0, 0)

// ---------------------------------------------------------------------------
// QKV GEMM: X fp32 [8192x768] @ W fp32 [768x2304] + b, truncation-split
// hi+lo bf16 (AhBh + AhBl + AlBh). Epilogue: Qh/Ql/Kh/Kl as [B,H,N,D];
// V stored TRANSPOSED [B,H,D,N] (packed uint2 stores) so attention reads
// PV B-fragments directly from global, no LDS transpose.
// ---------------------------------------------------------------------------
__global__ __launch_bounds__(256, 2)
void gemm_qkv(const float* __restrict__ X, const float* __restrict__ W,
              const float* __restrict__ bias,
              unsigned short* __restrict__ Qh, unsigned short* __restrict__ Ql,
              unsigned short* __restrict__ Kh, unsigned short* __restrict__ Kl,
              unsigned short* __restrict__ Vt)
{
    __shared__ unsigned short Ash[128][40], Asl[128][40];  // [row][k]
    __shared__ unsigned short Bsh[128][40], Bsl[128][40];  // [col][k] (B^T)

    const int tid  = threadIdx.x;
    const int wave = tid >> 6, lane = tid & 63;
    const int lr = lane & 15, lg = lane >> 4;
    const int wr = (wave >> 1) * 64, wc = (wave & 1) * 64;
    const int m0 = blockIdx.y * 128;
    const int c0 = blockIdx.x * 128;

    const f32x4 fzero = {0.f, 0.f, 0.f, 0.f};
    f32x4 acc[4][4];
    #pragma unroll
    for (int m = 0; m < 4; ++m)
        #pragma unroll
        for (int n = 0; n < 4; ++n) acc[m][n] = fzero;

    const int kgB = tid & 7;        // B-staging: 8 k-groups of 4
    const int cgB = tid >> 3;       // 32 col-groups of 4

    for (int k0 = 0; k0 < EMB; k0 += 32) {
        #pragma unroll
        for (int p = 0; p < 4; ++p) {
            int idx = (p << 8) + tid;
            int row = idx >> 3, kc = (idx & 7) << 2;
            f32x4 v = *reinterpret_cast<const f32x4*>(X + (size_t)(m0 + row) * EMB + k0 + kc);
            float l0 = v[0] - truncbf(v[0]), l1 = v[1] - truncbf(v[1]);
            float l2 = v[2] - truncbf(v[2]), l3 = v[3] - truncbf(v[3]);
            uint2 hw = { packtr(v[0], v[1]), packtr(v[2], v[3]) };
            uint2 lw = { packtr(l0, l1), packtr(l2, l3) };
            *reinterpret_cast<uint2*>(&Ash[row][kc]) = hw;
            *reinterpret_cast<uint2*>(&Asl[row][kc]) = lw;
        }
        {
            f32x4 v[4];
            #pragma unroll
            for (int i = 0; i < 4; ++i)
                v[i] = *reinterpret_cast<const f32x4*>(
                    W + (size_t)(k0 + kgB * 4 + i) * QKV_COLS + c0 + cgB * 4);
            #pragma unroll
            for (int j = 0; j < 4; ++j) {
                float a0 = v[0][j], a1 = v[1][j], a2 = v[2][j], a3 = v[3][j];
                float b0 = a0 - truncbf(a0), b1 = a1 - truncbf(a1);
                float b2 = a2 - truncbf(a2), b3 = a3 - truncbf(a3);
                uint2 hw = { packtr(a0, a1), packtr(a2, a3) };
                uint2 lw = { packtr(b0, b1), packtr(b2, b3) };
                *reinterpret_cast<uint2*>(&Bsh[cgB * 4 + j][kgB * 4]) = hw;
                *reinterpret_cast<uint2*>(&Bsl[cgB * 4 + j][kgB * 4]) = lw;
            }
        }
        __syncthreads();

        short8 ah[4], al[4], bh[4], bl[4];
        #pragma unroll
        for (int m = 0; m < 4; ++m) {
            ah[m] = *reinterpret_cast<const short8*>(&Ash[wr + m * 16 + lr][lg << 3]);
            al[m] = *reinterpret_cast<const short8*>(&Asl[wr + m * 16 + lr][lg << 3]);
        }
        #pragma unroll
        for (int n = 0; n < 4; ++n) {
            bh[n] = *reinterpret_cast<const short8*>(&Bsh[wc + n * 16 + lr][lg << 3]);
            bl[n] = *reinterpret_cast<const short8*>(&Bsl[wc + n * 16 + lr][lg << 3]);
        }
        #pragma unroll
        for (int m = 0; m < 4; ++m)
            #pragma unroll
            for (int n = 0; n < 4; ++n) {
                acc[m][n] = MFMA16(ah[m], bh[n], acc[m][n]);
                acc[m][n] = MFMA16(ah[m], bl[n], acc[m][n]);
                acc[m][n] = MFMA16(al[m], bh[n], acc[m][n]);
            }
        __syncthreads();
    }

    // epilogue: C/D layout col=lane&15, row=(lane>>4)*4+reg  [r8/r9-verified]
    #pragma unroll
    for (int m = 0; m < 4; ++m) {
        #pragma unroll
        for (int n = 0; n < 4; ++n) {
            const int colg = c0 + wc + n * 16 + lr;
            const float bv = bias[colg];
            const int which = colg % 3;
            const int h  = colg / 192;
            const int dd = (colg % 192) / 3;
            const int rowg0 = m0 + wr + m * 16 + (lg << 2);
            const int bi = rowg0 >> 10, ni0 = rowg0 & (SEQ - 1);
            const int bhid = bi * HEADS + h;
            if (which == 2) {
                // V transposed: [bh][dd][ni], 4 consecutive ni -> one uint2
                const float v0 = acc[m][n][0] + bv, v1 = acc[m][n][1] + bv;
                const float v2 = acc[m][n][2] + bv, v3 = acc[m][n][3] + bv;
                uint2 w = { (uint32_t)f2bf(v0) | ((uint32_t)f2bf(v1) << 16),
                            (uint32_t)f2bf(v2) | ((uint32_t)f2bf(v3) << 16) };
                *reinterpret_cast<uint2*>(Vt + ((size_t)bhid * HD + dd) * SEQ + ni0) = w;
            } else {
                unsigned short* __restrict__ Ph = (which == 0) ? Qh : Kh;
                unsigned short* __restrict__ Pl = (which == 0) ? Ql : Kl;
                #pragma unroll
                for (int j = 0; j < 4; ++j) {
                    const float val = acc[m][n][j] + bv;
                    const size_t oidx = ((size_t)bhid * SEQ + ni0 + j) * HD + dd;
                    const uint32_t uv = __float_as_uint(val);
                    Ph[oidx] = (unsigned short)(uv >> 16);
                    Pl[oidx] = (unsigned short)(__float_as_uint(
                        val - __uint_as_float(uv & 0xFFFF0000u)) >> 16);
                }
            }
        }
    }
}

// ---------------------------------------------------------------------------
// Flash attention, BARRIER-FREE: V^T pre-transposed in global, K direct
// from global (L2-resident), P via per-wave LDS (program-ordered, no sync).
// 4 waves x 16 q-rows per block; S = Qh*Kh + Ql*Kh + Qh*Kl (unscaled);
// softmax first; /sqrt(768) in output scale. XCD-swizzled block id.
// ---------------------------------------------------------------------------
__global__ __launch_bounds__(256, 4)
void attn_fused(const unsigned short* __restrict__ Qh, const unsigned short* __restrict__ Ql,
                const unsigned short* __restrict__ Kh, const unsigned short* __restrict__ Kl,
                const unsigned short* __restrict__ Vt,
                unsigned short* __restrict__ Ob)
{
    __shared__ unsigned short Plds[4][16][72];   // per-wave P: [qrow][key]

    const int tid  = threadIdx.x;
    const int wave = tid >> 6, lane = tid & 63;
    const int lr = lane & 15, lg = lane >> 4;

    // bijective XCD swizzle: 1536 blocks = 8 * 192; same-bh blocks same XCD
    const int bid = blockIdx.x;
    const int lid = (bid & 7) * 192 + (bid >> 3);
    const int qt = lid & 15;            // 0..15
    const int bh = lid >> 4;            // 0..95
    const int b = bh / HEADS, h = bh % HEADS;

    const size_t base = (size_t)bh * SEQ * HD;
    const unsigned short* Qhb = Qh + base;
    const unsigned short* Qlb = Ql + base;
    const unsigned short* Khb = Kh + base;
    const unsigned short* Klb = Kl + base;
    const unsigned short* Vtb = Vt + base;      // [HD][SEQ]

    const int q0 = qt * 64 + wave * 16;

    short8 qh[2], ql[2];
    #pragma unroll
    for (int kk = 0; kk < 2; ++kk) {
        const size_t off = (size_t)(q0 + lr) * HD + kk * 32 + (lg << 3);
        qh[kk] = *reinterpret_cast<const short8*>(Qhb + off);
        ql[kk] = *reinterpret_cast<const short8*>(Qlb + off);
    }

    float mrow[4], lrow[4];
    f32x4 oacc[4];
    const f32x4 fzero = {0.f, 0.f, 0.f, 0.f};
    #pragma unroll
    for (int j = 0; j < 4; ++j) { mrow[j] = -1.0e30f; lrow[j] = 0.f; }
    #pragma unroll
    for (int d = 0; d < 4; ++d) oacc[d] = fzero;

    for (int t = 0; t < SEQ / 64; ++t) {
        const int kbase = t * 64;

        // S = Q K^T (direct global loads, L2-resident)
        f32x4 s[4];
        #pragma unroll
        for (int n = 0; n < 4; ++n) s[n] = fzero;
        #pragma unroll
        for (int n = 0; n < 4; ++n) {
            #pragma unroll
            for (int kk = 0; kk < 2; ++kk) {
                const size_t koff = (size_t)(kbase + n * 16 + lr) * HD + kk * 32 + (lg << 3);
                const short8 kh = *reinterpret_cast<const short8*>(Khb + koff);
                const short8 kl = *reinterpret_cast<const short8*>(Klb + koff);
                s[n] = MFMA16(qh[kk], kh, s[n]);
                s[n] = MFMA16(ql[kk], kh, s[n]);
                s[n] = MFMA16(qh[kk], kl, s[n]);
            }
        }

        // online softmax (per-wave, no barriers)
        #pragma unroll
        for (int j = 0; j < 4; ++j) {
            float tmax = fmaxf(fmaxf(s[0][j], s[1][j]), fmaxf(s[2][j], s[3][j]));
            #pragma unroll
            for (int off = 8; off >= 1; off >>= 1)
                tmax = fmaxf(tmax, __shfl_xor(tmax, off, 16));
            const float mnew = fmaxf(mrow[j], tmax);
            const float corr = __expf(mrow[j] - mnew);
            mrow[j] = mnew;
            float psum = 0.f;
            #pragma unroll
            for (int n = 0; n < 4; ++n) {
                const float p = __expf(s[n][j] - mnew);
                psum += p;
                Plds[wave][(lg << 2) + j][n * 16 + lr] = f2bf(p);
            }
            #pragma unroll
            for (int off = 8; off >= 1; off >>= 1)
                psum += __shfl_xor(psum, off, 16);
            lrow[j] = lrow[j] * corr + psum;
            #pragma unroll
            for (int d = 0; d < 4; ++d) oacc[d][j] *= corr;
        }

        // O += P V  (A = P from per-wave LDS; B = V^T rows direct from global)
        #pragma unroll
        for (int kk = 0; kk < 2; ++kk) {
            const short8 ap = *reinterpret_cast<const short8*>(&Plds[wave][lr][kk * 32 + (lg << 3)]);
            #pragma unroll
            for (int d = 0; d < 4; ++d) {
                const short8 bv = *reinterpret_cast<const short8*>(
                    Vtb + (size_t)(d * 16 + lr) * SEQ + kbase + kk * 32 + (lg << 3));
                oacc[d] = MFMA16(ap, bv, oacc[d]);
            }
        }
    }

    const float rs = 0.036084391824351615f;  // 1/sqrt(768)
    #pragma unroll
    for (int j = 0; j < 4; ++j) {
        const float sc = rs / lrow[j];
        const int q = q0 + (lg << 2) + j;
        #pragma unroll
        for (int d = 0; d < 4; ++d) {
            const float val = oacc[d][j] * sc;
            Ob[((size_t)b * SEQ + q) * EMB + h * HD + d * 16 + lr] = f2bf(val);
        }
    }
}

// ---------------------------------------------------------------------------
// Proj GEMM (MFMA): Ob bf16 [8192x768] @ W_proj (fp32 -> bf16 RN) + b
// -> fp32 d_out.
// ---------------------------------------------------------------------------
__global__ __launch_bounds__(256, 2)
void gemm_proj(const unsigned short* __restrict__ A, const float* __restrict__ W,
               const float* __restrict__ bias, float* __restrict__ Out)
{
    __shared__ unsigned short As[128][40];
    __shared__ unsigned short Bs[128][40];

    const int tid  = threadIdx.x;
    const int wave = tid >> 6, lane = tid & 63;
    const int lr = lane & 15, lg = lane >> 4;
    const int wr = (wave >> 1) * 64, wc = (wave & 1) * 64;
    const int m0 = blockIdx.y * 128;
    const int c0 = blockIdx.x * 128;

    const f32x4 fzero = {0.f, 0.f, 0.f, 0.f};
    f32x4 acc[4][4];
    #pragma unroll
    for (int m = 0; m < 4; ++m)
        #pragma unroll
        for (int n = 0; n < 4; ++n) acc[m][n] = fzero;

    const int kgB = tid & 7, cgB = tid >> 3;

    for (int k0 = 0; k0 < EMB; k0 += 32) {
        #pragma unroll
        for (int p = 0; p < 2; ++p) {
            int idx = (p << 8) + tid;
            int row = idx >> 2, kc = (idx & 3) << 3;
            uint4 v = *reinterpret_cast<const uint4*>(A + (size_t)(m0 + row) * EMB + k0 + kc);
            *reinterpret_cast<uint4*>(&As[row][kc]) = v;
        }
        {
            f32x4 v[4];
            #pragma unroll
            for (int i = 0; i < 4; ++i)
                v[i] = *reinterpret_cast<const f32x4*>(
                    W + (size_t)(k0 + kgB * 4 + i) * EMB + c0 + cgB * 4);
            #pragma unroll
            for (int j = 0; j < 4; ++j) {
                uint2 w = { (uint32_t)f2bf(v[0][j]) | ((uint32_t)f2bf(v[1][j]) << 16),
                            (uint32_t)f2bf(v[2][j]) | ((uint32_t)f2bf(v[3][j]) << 16) };
                *reinterpret_cast<uint2*>(&Bs[cgB * 4 + j][kgB * 4]) = w;
            }
        }
        __syncthreads();

        short8 a[4], b[4];
        #pragma unroll
        for (int m = 0; m < 4; ++m)
            a[m] = *reinterpret_cast<const short8*>(&As[wr + m * 16 + lr][lg << 3]);
        #pragma unroll
        for (int n = 0; n < 4; ++n)
            b[n] = *reinterpret_cast<const short8*>(&Bs[wc + n * 16 + lr][lg << 3]);
        #pragma unroll
        for (int m = 0; m < 4; ++m)
            #pragma unroll
            for (int n = 0; n < 4; ++n)
                acc[m][n] = MFMA16(a[m], b[n], acc[m][n]);
        __syncthreads();
    }

    #pragma unroll
    for (int m = 0; m < 4; ++m) {
        #pragma unroll
        for (int n = 0; n < 4; ++n) {
            const int colg = c0 + wc + n * 16 + lr;
            const float bv = bias[colg];
            #pragma unroll
            for (int j = 0; j < 4; ++j) {
                const int rowg = m0 + wr + m * 16 + (lg << 2) + j;
                Out[(size_t)rowg * EMB + colg] = acc[m][n][j] + bv;   // fp32 out
            }
        }
    }
}

// ---------------------------------------------------------------------------
extern "C" void kernel_launch(void* const* d_in, const int* in_sizes, int n_in,
                              void* d_out, int out_size, void* d_ws, size_t ws_size,
                              hipStream_t stream)
{
    const float* x     = (const float*)d_in[0];
    const float* Wqkv  = (const float*)d_in[1];
    const float* bqkv  = (const float*)d_in[2];
    const float* Wproj = (const float*)d_in[3];
    const float* bproj = (const float*)d_in[4];
    float* out = (float*)d_out;    // reference output dtype = float32

    const size_t NQ = (size_t)BATCH * HEADS * SEQ * HD;  // 6291456
    unsigned short* Qh = (unsigned short*)d_ws;
    unsigned short* Ql = Qh + NQ;
    unsigned short* Kh = Ql + NQ;
    unsigned short* Kl = Kh + NQ;
    unsigned short* Vt = Kl + NQ;                        // [B,H,D,N] transposed
    unsigned short* Ob = Vt + NQ;                        // total 75.5 MB

    gemm_qkv<<<dim3(QKV_COLS / 128, M_ROWS / 128), 256, 0, stream>>>(
        x, Wqkv, bqkv, Qh, Ql, Kh, Kl, Vt);
    attn_fused<<<dim3(16 * BATCH * HEADS), 256, 0, stream>>>(Qh, Ql, Kh, Kl, Vt, Ob);
    gemm_proj<<<dim3(EMB / 128, M_ROWS / 128), 256, 0, stream>>>(
        Ob, Wproj, bproj, out);
}

// Round 11
// 379.454 us; speedup vs baseline: 1.1666x; 1.1666x over previous
//
#include <hip/hip_runtime.h>
#include <hip/hip_bf16.h>
#include <stdint.h>

#define EMB 768
#define HEADS 12
#define BATCH 8
#define SEQ 1024
#define HD 64
#define M_ROWS (BATCH * SEQ)   /* 8192 */
#define QKV_COLS (3 * EMB)     /* 2304 */

typedef __attribute__((ext_vector_type(8))) short short8;
typedef __attribute__((ext_vector_type(4))) float f32x4;

__device__ __forceinline__ unsigned short f2bf(float x) {
    union { float f; unsigned u; } v; v.f = x;
    unsigned r = v.u + 0x7FFFu + ((v.u >> 16) & 1u);
    return (unsigned short)(r >> 16);
}
__device__ __forceinline__ float bf2f(unsigned short h) {
    union { unsigned u; float f; } v; v.u = ((unsigned)h) << 16;
    return v.f;
}
__device__ __forceinline__ float truncbf(float x) {
    return __uint_as_float(__float_as_uint(x) & 0xFFFF0000u);
}
__device__ __forceinline__ uint32_t packtr(float a, float b) {   // lo16=tr(a), hi16=tr(b)
    return (__float_as_uint(a) >> 16) | (__float_as_uint(b) & 0xFFFF0000u);
}

#define MFMA16(a, b, c) __builtin_amdgcn_mfma_f32_16x16x32_bf16((a), (b), (c), 0, 0, 0)

// ---------------------------------------------------------------------------
// QKV GEMM (r10-verified): X fp32 @ W fp32 + b, truncation-split hi+lo bf16
// (AhBh + AhBl + AlBh). Epilogue: Qh/Ql/Kh/Kl [B,H,N,D]; V TRANSPOSED [B,H,D,N].
// ---------------------------------------------------------------------------
__global__ __launch_bounds__(256, 2)
void gemm_qkv(const float* __restrict__ X, const float* __restrict__ W,
              const float* __restrict__ bias,
              unsigned short* __restrict__ Qh, unsigned short* __restrict__ Ql,
              unsigned short* __restrict__ Kh, unsigned short* __restrict__ Kl,
              unsigned short* __restrict__ Vt)
{
    __shared__ unsigned short Ash[128][40], Asl[128][40];  // [row][k]
    __shared__ unsigned short Bsh[128][40], Bsl[128][40];  // [col][k] (B^T)

    const int tid  = threadIdx.x;
    const int wave = tid >> 6, lane = tid & 63;
    const int lr = lane & 15, lg = lane >> 4;
    const int wr = (wave >> 1) * 64, wc = (wave & 1) * 64;
    const int m0 = blockIdx.y * 128;
    const int c0 = blockIdx.x * 128;

    const f32x4 fzero = {0.f, 0.f, 0.f, 0.f};
    f32x4 acc[4][4];
    #pragma unroll
    for (int m = 0; m < 4; ++m)
        #pragma unroll
        for (int n = 0; n < 4; ++n) acc[m][n] = fzero;

    const int kgB = tid & 7;        // B-staging: 8 k-groups of 4
    const int cgB = tid >> 3;       // 32 col-groups of 4

    for (int k0 = 0; k0 < EMB; k0 += 32) {
        #pragma unroll
        for (int p = 0; p < 4; ++p) {
            int idx = (p << 8) + tid;
            int row = idx >> 3, kc = (idx & 7) << 2;
            f32x4 v = *reinterpret_cast<const f32x4*>(X + (size_t)(m0 + row) * EMB + k0 + kc);
            float l0 = v[0] - truncbf(v[0]), l1 = v[1] - truncbf(v[1]);
            float l2 = v[2] - truncbf(v[2]), l3 = v[3] - truncbf(v[3]);
            uint2 hw = { packtr(v[0], v[1]), packtr(v[2], v[3]) };
            uint2 lw = { packtr(l0, l1), packtr(l2, l3) };
            *reinterpret_cast<uint2*>(&Ash[row][kc]) = hw;
            *reinterpret_cast<uint2*>(&Asl[row][kc]) = lw;
        }
        {
            f32x4 v[4];
            #pragma unroll
            for (int i = 0; i < 4; ++i)
                v[i] = *reinterpret_cast<const f32x4*>(
                    W + (size_t)(k0 + kgB * 4 + i) * QKV_COLS + c0 + cgB * 4);
            #pragma unroll
            for (int j = 0; j < 4; ++j) {
                float a0 = v[0][j], a1 = v[1][j], a2 = v[2][j], a3 = v[3][j];
                float b0 = a0 - truncbf(a0), b1 = a1 - truncbf(a1);
                float b2 = a2 - truncbf(a2), b3 = a3 - truncbf(a3);
                uint2 hw = { packtr(a0, a1), packtr(a2, a3) };
                uint2 lw = { packtr(b0, b1), packtr(b2, b3) };
                *reinterpret_cast<uint2*>(&Bsh[cgB * 4 + j][kgB * 4]) = hw;
                *reinterpret_cast<uint2*>(&Bsl[cgB * 4 + j][kgB * 4]) = lw;
            }
        }
        __syncthreads();

        short8 ah[4], al[4], bh[4], bl[4];
        #pragma unroll
        for (int m = 0; m < 4; ++m) {
            ah[m] = *reinterpret_cast<const short8*>(&Ash[wr + m * 16 + lr][lg << 3]);
            al[m] = *reinterpret_cast<const short8*>(&Asl[wr + m * 16 + lr][lg << 3]);
        }
        #pragma unroll
        for (int n = 0; n < 4; ++n) {
            bh[n] = *reinterpret_cast<const short8*>(&Bsh[wc + n * 16 + lr][lg << 3]);
            bl[n] = *reinterpret_cast<const short8*>(&Bsl[wc + n * 16 + lr][lg << 3]);
        }
        #pragma unroll
        for (int m = 0; m < 4; ++m)
            #pragma unroll
            for (int n = 0; n < 4; ++n) {
                acc[m][n] = MFMA16(ah[m], bh[n], acc[m][n]);
                acc[m][n] = MFMA16(ah[m], bl[n], acc[m][n]);
                acc[m][n] = MFMA16(al[m], bh[n], acc[m][n]);
            }
        __syncthreads();
    }

    // epilogue: C/D layout col=lane&15, row=(lane>>4)*4+reg  [r8/r9/r10-verified]
    #pragma unroll
    for (int m = 0; m < 4; ++m) {
        #pragma unroll
        for (int n = 0; n < 4; ++n) {
            const int colg = c0 + wc + n * 16 + lr;
            const float bv = bias[colg];
            const int which = colg % 3;
            const int h  = colg / 192;
            const int dd = (colg % 192) / 3;
            const int rowg0 = m0 + wr + m * 16 + (lg << 2);
            const int bi = rowg0 >> 10, ni0 = rowg0 & (SEQ - 1);
            const int bhid = bi * HEADS + h;
            if (which == 2) {
                const float v0 = acc[m][n][0] + bv, v1 = acc[m][n][1] + bv;
                const float v2 = acc[m][n][2] + bv, v3 = acc[m][n][3] + bv;
                uint2 w = { (uint32_t)f2bf(v0) | ((uint32_t)f2bf(v1) << 16),
                            (uint32_t)f2bf(v2) | ((uint32_t)f2bf(v3) << 16) };
                *reinterpret_cast<uint2*>(Vt + ((size_t)bhid * HD + dd) * SEQ + ni0) = w;
            } else {
                unsigned short* __restrict__ Ph = (which == 0) ? Qh : Kh;
                unsigned short* __restrict__ Pl = (which == 0) ? Ql : Kl;
                #pragma unroll
                for (int j = 0; j < 4; ++j) {
                    const float val = acc[m][n][j] + bv;
                    const size_t oidx = ((size_t)bhid * SEQ + ni0 + j) * HD + dd;
                    const uint32_t uv = __float_as_uint(val);
                    Ph[oidx] = (unsigned short)(uv >> 16);
                    Pl[oidx] = (unsigned short)(__float_as_uint(
                        val - __uint_as_float(uv & 0xFFFF0000u)) >> 16);
                }
            }
        }
    }
}

// ---------------------------------------------------------------------------
// Flash attention (r9 structure + r10's proven mechanisms):
//  - LDS-staged V tile (straight copy from pre-transposed Vt -> conflict-free)
//  - barriers retained (burst staging, latency-tolerant)
//  - XCD-swizzled flat grid (L2 locality: FETCH 160->31MB proven in r10)
// ---------------------------------------------------------------------------
__global__ __launch_bounds__(256, 2)
void attn_fused(const unsigned short* __restrict__ Qh, const unsigned short* __restrict__ Ql,
                const unsigned short* __restrict__ Kh, const unsigned short* __restrict__ Kl,
                const unsigned short* __restrict__ Vt,
                unsigned short* __restrict__ Ob)
{
    __shared__ unsigned short Vs[64][72];        // V^T tile: [d][key]
    __shared__ unsigned short Plds[4][16][72];   // per-wave P: [qrow][key]

    const int tid  = threadIdx.x;
    const int wave = tid >> 6, lane = tid & 63;
    const int lr = lane & 15, lg = lane >> 4;

    // bijective XCD swizzle: 1536 = 8 * 192; same-bh blocks on one XCD
    const int bid = blockIdx.x;
    const int lid = (bid & 7) * 192 + (bid >> 3);
    const int qt = lid & 15;            // 0..15
    const int bh = lid >> 4;            // 0..95
    const int b = bh / HEADS, h = bh % HEADS;

    const size_t base = (size_t)bh * SEQ * HD;
    const unsigned short* Qhb = Qh + base;
    const unsigned short* Qlb = Ql + base;
    const unsigned short* Khb = Kh + base;
    const unsigned short* Klb = Kl + base;
    const unsigned short* Vtb = Vt + base;      // [HD][SEQ]

    const int q0 = qt * 64 + wave * 16;

    short8 qh[2], ql[2];
    #pragma unroll
    for (int kk = 0; kk < 2; ++kk) {
        const size_t off = (size_t)(q0 + lr) * HD + kk * 32 + (lg << 3);
        qh[kk] = *reinterpret_cast<const short8*>(Qhb + off);
        ql[kk] = *reinterpret_cast<const short8*>(Qlb + off);
    }

    float mrow[4], lrow[4];
    f32x4 oacc[4];
    const f32x4 fzero = {0.f, 0.f, 0.f, 0.f};
    #pragma unroll
    for (int j = 0; j < 4; ++j) { mrow[j] = -1.0e30f; lrow[j] = 0.f; }
    #pragma unroll
    for (int d = 0; d < 4; ++d) oacc[d] = fzero;

    for (int t = 0; t < SEQ / 64; ++t) {
        const int kbase = t * 64;

        __syncthreads();                 // all waves done reading previous Vs
        // stage V^T tile: straight 16B copy (V already transposed in global)
        // writes: bank = 4*(d + (tid&7)) mod 32 -> uniform 8/bank, conflict-free
        #pragma unroll
        for (int p = 0; p < 2; ++p) {
            int idx = (p << 8) + tid;
            int d = idx >> 3, kc = (idx & 7) << 3;
            *reinterpret_cast<uint4*>(&Vs[d][kc]) =
                *reinterpret_cast<const uint4*>(Vtb + (size_t)d * SEQ + kbase + kc);
        }
        __syncthreads();

        // S = Q K^T (K direct from global / L2)
        f32x4 s[4];
        #pragma unroll
        for (int n = 0; n < 4; ++n) s[n] = fzero;
        #pragma unroll
        for (int n = 0; n < 4; ++n) {
            #pragma unroll
            for (int kk = 0; kk < 2; ++kk) {
                const size_t koff = (size_t)(kbase + n * 16 + lr) * HD + kk * 32 + (lg << 3);
                const short8 kh = *reinterpret_cast<const short8*>(Khb + koff);
                const short8 kl = *reinterpret_cast<const short8*>(Klb + koff);
                s[n] = MFMA16(qh[kk], kh, s[n]);
                s[n] = MFMA16(ql[kk], kh, s[n]);
                s[n] = MFMA16(qh[kk], kl, s[n]);
            }
        }

        // online softmax
        #pragma unroll
        for (int j = 0; j < 4; ++j) {
            float tmax = fmaxf(fmaxf(s[0][j], s[1][j]), fmaxf(s[2][j], s[3][j]));
            #pragma unroll
            for (int off = 8; off >= 1; off >>= 1)
                tmax = fmaxf(tmax, __shfl_xor(tmax, off, 16));
            const float mnew = fmaxf(mrow[j], tmax);
            const float corr = __expf(mrow[j] - mnew);
            mrow[j] = mnew;
            float psum = 0.f;
            #pragma unroll
            for (int n = 0; n < 4; ++n) {
                const float p = __expf(s[n][j] - mnew);
                psum += p;
                Plds[wave][(lg << 2) + j][n * 16 + lr] = f2bf(p);
            }
            #pragma unroll
            for (int off = 8; off >= 1; off >>= 1)
                psum += __shfl_xor(psum, off, 16);
            lrow[j] = lrow[j] * corr + psum;
            #pragma unroll
            for (int d = 0; d < 4; ++d) oacc[d][j] *= corr;
        }

        // O += P V  (A = P from per-wave LDS; B = V^T from LDS)
        #pragma unroll
        for (int kk = 0; kk < 2; ++kk) {
            const short8 ap = *reinterpret_cast<const short8*>(&Plds[wave][lr][kk * 32 + (lg << 3)]);
            #pragma unroll
            for (int d = 0; d < 4; ++d) {
                const short8 bv = *reinterpret_cast<const short8*>(&Vs[d * 16 + lr][kk * 32 + (lg << 3)]);
                oacc[d] = MFMA16(ap, bv, oacc[d]);
            }
        }
    }

    const float rs = 0.036084391824351615f;  // 1/sqrt(768)
    #pragma unroll
    for (int j = 0; j < 4; ++j) {
        const float sc = rs / lrow[j];
        const int q = q0 + (lg << 2) + j;
        #pragma unroll
        for (int d = 0; d < 4; ++d) {
            const float val = oacc[d][j] * sc;
            Ob[((size_t)b * SEQ + q) * EMB + h * HD + d * 16 + lr] = f2bf(val);
        }
    }
}

// ---------------------------------------------------------------------------
// Proj GEMM (r9-verified): Ob bf16 @ W_proj (fp32->bf16 RN) + b -> fp32 d_out.
// ---------------------------------------------------------------------------
__global__ __launch_bounds__(256, 2)
void gemm_proj(const unsigned short* __restrict__ A, const float* __restrict__ W,
               const float* __restrict__ bias, float* __restrict__ Out)
{
    __shared__ unsigned short As[128][40];
    __shared__ unsigned short Bs[128][40];

    const int tid  = threadIdx.x;
    const int wave = tid >> 6, lane = tid & 63;
    const int lr = lane & 15, lg = lane >> 4;
    const int wr = (wave >> 1) * 64, wc = (wave & 1) * 64;
    const int m0 = blockIdx.y * 128;
    const int c0 = blockIdx.x * 128;

    const f32x4 fzero = {0.f, 0.f, 0.f, 0.f};
    f32x4 acc[4][4];
    #pragma unroll
    for (int m = 0; m < 4; ++m)
        #pragma unroll
        for (int n = 0; n < 4; ++n) acc[m][n] = fzero;

    const int kgB = tid & 7, cgB = tid >> 3;

    for (int k0 = 0; k0 < EMB; k0 += 32) {
        #pragma unroll
        for (int p = 0; p < 2; ++p) {
            int idx = (p << 8) + tid;
            int row = idx >> 2, kc = (idx & 3) << 3;
            uint4 v = *reinterpret_cast<const uint4*>(A + (size_t)(m0 + row) * EMB + k0 + kc);
            *reinterpret_cast<uint4*>(&As[row][kc]) = v;
        }
        {
            f32x4 v[4];
            #pragma unroll
            for (int i = 0; i < 4; ++i)
                v[i] = *reinterpret_cast<const f32x4*>(
                    W + (size_t)(k0 + kgB * 4 + i) * EMB + c0 + cgB * 4);
            #pragma unroll
            for (int j = 0; j < 4; ++j) {
                uint2 w = { (uint32_t)f2bf(v[0][j]) | ((uint32_t)f2bf(v[1][j]) << 16),
                            (uint32_t)f2bf(v[2][j]) | ((uint32_t)f2bf(v[3][j]) << 16) };
                *reinterpret_cast<uint2*>(&Bs[cgB * 4 + j][kgB * 4]) = w;
            }
        }
        __syncthreads();

        short8 a[4], b[4];
        #pragma unroll
        for (int m = 0; m < 4; ++m)
            a[m] = *reinterpret_cast<const short8*>(&As[wr + m * 16 + lr][lg << 3]);
        #pragma unroll
        for (int n = 0; n < 4; ++n)
            b[n] = *reinterpret_cast<const short8*>(&Bs[wc + n * 16 + lr][lg << 3]);
        #pragma unroll
        for (int m = 0; m < 4; ++m)
            #pragma unroll
            for (int n = 0; n < 4; ++n)
                acc[m][n] = MFMA16(a[m], b[n], acc[m][n]);
        __syncthreads();
    }

    #pragma unroll
    for (int m = 0; m < 4; ++m) {
        #pragma unroll
        for (int n = 0; n < 4; ++n) {
            const int colg = c0 + wc + n * 16 + lr;
            const float bv = bias[colg];
            #pragma unroll
            for (int j = 0; j < 4; ++j) {
                const int rowg = m0 + wr + m * 16 + (lg << 2) + j;
                Out[(size_t)rowg * EMB + colg] = acc[m][n][j] + bv;   // fp32 out
            }
        }
    }
}

// ---------------------------------------------------------------------------
extern "C" void kernel_launch(void* const* d_in, const int* in_sizes, int n_in,
                              void* d_out, int out_size, void* d_ws, size_t ws_size,
                              hipStream_t stream)
{
    const float* x     = (const float*)d_in[0];
    const float* Wqkv  = (const float*)d_in[1];
    const float* bqkv  = (const float*)d_in[2];
    const float* Wproj = (const float*)d_in[3];
    const float* bproj = (const float*)d_in[4];
    float* out = (float*)d_out;    // reference output dtype = float32

    const size_t NQ = (size_t)BATCH * HEADS * SEQ * HD;  // 6291456
    unsigned short* Qh = (unsigned short*)d_ws;
    unsigned short* Ql = Qh + NQ;
    unsigned short* Kh = Ql + NQ;
    unsigned short* Kl = Kh + NQ;
    unsigned short* Vt = Kl + NQ;                        // [B,H,D,N] transposed
    unsigned short* Ob = Vt + NQ;                        // total 75.5 MB

    gemm_qkv<<<dim3(QKV_COLS / 128, M_ROWS / 128), 256, 0, stream>>>(
        x, Wqkv, bqkv, Qh, Ql, Kh, Kl, Vt);
    attn_fused<<<dim3(16 * BATCH * HEADS), 256, 0, stream>>>(Qh, Ql, Kh, Kl, Vt, Ob);
    gemm_proj<<<dim3(EMB / 128, M_ROWS / 128), 256, 0, stream>>>(
        Ob, Wproj, bproj, out);
}

// Round 12
// 244.121 us; speedup vs baseline: 1.8134x; 1.5544x over previous
//
#include <hip/hip_runtime.h>
#include <hip/hip_bf16.h>
#include <stdint.h>

#define EMB 768
#define HEADS 12
#define BATCH 8
#define SEQ 1024
#define HD 64
#define M_ROWS (BATCH * SEQ)   /* 8192 */
#define QKV_COLS (3 * EMB)     /* 2304 */

typedef __attribute__((ext_vector_type(8))) short short8;
typedef __attribute__((ext_vector_type(4))) float f32x4;

__device__ __forceinline__ unsigned short f2bf(float x) {
    union { float f; unsigned u; } v; v.f = x;
    unsigned r = v.u + 0x7FFFu + ((v.u >> 16) & 1u);
    return (unsigned short)(r >> 16);
}
__device__ __forceinline__ float bf2f(unsigned short h) {
    union { unsigned u; float f; } v; v.u = ((unsigned)h) << 16;
    return v.f;
}
__device__ __forceinline__ float truncbf(float x) {
    return __uint_as_float(__float_as_uint(x) & 0xFFFF0000u);
}
__device__ __forceinline__ uint32_t packtr(float a, float b) {   // lo16=tr(a), hi16=tr(b)
    return (__float_as_uint(a) >> 16) | (__float_as_uint(b) & 0xFFFF0000u);
}

#define MFMA16(a, b, c) __builtin_amdgcn_mfma_f32_16x16x32_bf16((a), (b), (c), 0, 0, 0)

// ---------------------------------------------------------------------------
// QKV GEMM (r10/r11-verified): X fp32 @ W fp32 + b, truncation-split hi+lo
// bf16 (AhBh + AhBl + AlBh). Epilogue: Qh/Ql/Kh/Kl [B,H,N,D]; V [B,H,D,N].
// ---------------------------------------------------------------------------
__global__ __launch_bounds__(256, 2)
void gemm_qkv(const float* __restrict__ X, const float* __restrict__ W,
              const float* __restrict__ bias,
              unsigned short* __restrict__ Qh, unsigned short* __restrict__ Ql,
              unsigned short* __restrict__ Kh, unsigned short* __restrict__ Kl,
              unsigned short* __restrict__ Vt)
{
    __shared__ unsigned short Ash[128][40], Asl[128][40];  // [row][k]
    __shared__ unsigned short Bsh[128][40], Bsl[128][40];  // [col][k] (B^T)

    const int tid  = threadIdx.x;
    const int wave = tid >> 6, lane = tid & 63;
    const int lr = lane & 15, lg = lane >> 4;
    const int wr = (wave >> 1) * 64, wc = (wave & 1) * 64;
    const int m0 = blockIdx.y * 128;
    const int c0 = blockIdx.x * 128;

    const f32x4 fzero = {0.f, 0.f, 0.f, 0.f};
    f32x4 acc[4][4];
    #pragma unroll
    for (int m = 0; m < 4; ++m)
        #pragma unroll
        for (int n = 0; n < 4; ++n) acc[m][n] = fzero;

    const int kgB = tid & 7;        // B-staging: 8 k-groups of 4
    const int cgB = tid >> 3;       // 32 col-groups of 4

    for (int k0 = 0; k0 < EMB; k0 += 32) {
        #pragma unroll
        for (int p = 0; p < 4; ++p) {
            int idx = (p << 8) + tid;
            int row = idx >> 3, kc = (idx & 7) << 2;
            f32x4 v = *reinterpret_cast<const f32x4*>(X + (size_t)(m0 + row) * EMB + k0 + kc);
            float l0 = v[0] - truncbf(v[0]), l1 = v[1] - truncbf(v[1]);
            float l2 = v[2] - truncbf(v[2]), l3 = v[3] - truncbf(v[3]);
            uint2 hw = { packtr(v[0], v[1]), packtr(v[2], v[3]) };
            uint2 lw = { packtr(l0, l1), packtr(l2, l3) };
            *reinterpret_cast<uint2*>(&Ash[row][kc]) = hw;
            *reinterpret_cast<uint2*>(&Asl[row][kc]) = lw;
        }
        {
            f32x4 v[4];
            #pragma unroll
            for (int i = 0; i < 4; ++i)
                v[i] = *reinterpret_cast<const f32x4*>(
                    W + (size_t)(k0 + kgB * 4 + i) * QKV_COLS + c0 + cgB * 4);
            #pragma unroll
            for (int j = 0; j < 4; ++j) {
                float a0 = v[0][j], a1 = v[1][j], a2 = v[2][j], a3 = v[3][j];
                float b0 = a0 - truncbf(a0), b1 = a1 - truncbf(a1);
                float b2 = a2 - truncbf(a2), b3 = a3 - truncbf(a3);
                uint2 hw = { packtr(a0, a1), packtr(a2, a3) };
                uint2 lw = { packtr(b0, b1), packtr(b2, b3) };
                *reinterpret_cast<uint2*>(&Bsh[cgB * 4 + j][kgB * 4]) = hw;
                *reinterpret_cast<uint2*>(&Bsl[cgB * 4 + j][kgB * 4]) = lw;
            }
        }
        __syncthreads();

        short8 ah[4], al[4], bh[4], bl[4];
        #pragma unroll
        for (int m = 0; m < 4; ++m) {
            ah[m] = *reinterpret_cast<const short8*>(&Ash[wr + m * 16 + lr][lg << 3]);
            al[m] = *reinterpret_cast<const short8*>(&Asl[wr + m * 16 + lr][lg << 3]);
        }
        #pragma unroll
        for (int n = 0; n < 4; ++n) {
            bh[n] = *reinterpret_cast<const short8*>(&Bsh[wc + n * 16 + lr][lg << 3]);
            bl[n] = *reinterpret_cast<const short8*>(&Bsl[wc + n * 16 + lr][lg << 3]);
        }
        #pragma unroll
        for (int m = 0; m < 4; ++m)
            #pragma unroll
            for (int n = 0; n < 4; ++n) {
                acc[m][n] = MFMA16(ah[m], bh[n], acc[m][n]);
                acc[m][n] = MFMA16(ah[m], bl[n], acc[m][n]);
                acc[m][n] = MFMA16(al[m], bh[n], acc[m][n]);
            }
        __syncthreads();
    }

    #pragma unroll
    for (int m = 0; m < 4; ++m) {
        #pragma unroll
        for (int n = 0; n < 4; ++n) {
            const int colg = c0 + wc + n * 16 + lr;
            const float bv = bias[colg];
            const int which = colg % 3;
            const int h  = colg / 192;
            const int dd = (colg % 192) / 3;
            const int rowg0 = m0 + wr + m * 16 + (lg << 2);
            const int bi = rowg0 >> 10, ni0 = rowg0 & (SEQ - 1);
            const int bhid = bi * HEADS + h;
            if (which == 2) {
                const float v0 = acc[m][n][0] + bv, v1 = acc[m][n][1] + bv;
                const float v2 = acc[m][n][2] + bv, v3 = acc[m][n][3] + bv;
                uint2 w = { (uint32_t)f2bf(v0) | ((uint32_t)f2bf(v1) << 16),
                            (uint32_t)f2bf(v2) | ((uint32_t)f2bf(v3) << 16) };
                *reinterpret_cast<uint2*>(Vt + ((size_t)bhid * HD + dd) * SEQ + ni0) = w;
            } else {
                unsigned short* __restrict__ Ph = (which == 0) ? Qh : Kh;
                unsigned short* __restrict__ Pl = (which == 0) ? Ql : Kl;
                #pragma unroll
                for (int j = 0; j < 4; ++j) {
                    const float val = acc[m][n][j] + bv;
                    const size_t oidx = ((size_t)bhid * SEQ + ni0 + j) * HD + dd;
                    const uint32_t uv = __float_as_uint(val);
                    Ph[oidx] = (unsigned short)(uv >> 16);
                    Pl[oidx] = (unsigned short)(__float_as_uint(
                        val - __uint_as_float(uv & 0xFFFF0000u)) >> 16);
                }
            }
        }
    }
}

// ---------------------------------------------------------------------------
// Flash attention v3: swapped QK^T (S^T = mfma(K,Q)) -> softmax reduce is
// in-lane (15 VALU) + 2 shfl, vs 32 serial shuffles before. K (h+l) and V^T
// staged in LDS per tile (one burst, no 4x duplicate L2 reads).
// ---------------------------------------------------------------------------
__global__ __launch_bounds__(256, 2)
void attn_fused(const unsigned short* __restrict__ Qh, const unsigned short* __restrict__ Ql,
                const unsigned short* __restrict__ Kh, const unsigned short* __restrict__ Kl,
                const unsigned short* __restrict__ Vt,
                unsigned short* __restrict__ Ob)
{
    __shared__ unsigned short Vs[64][72];        // V^T tile: [d][key]
    __shared__ unsigned short Ksh[64][72];       // K hi tile: [key][d]
    __shared__ unsigned short Ksl[64][72];       // K lo tile: [key][d]
    __shared__ unsigned short Plds[4][16][72];   // per-wave P: [qrow][key]

    const int tid  = threadIdx.x;
    const int wave = tid >> 6, lane = tid & 63;
    const int lr = lane & 15, lg = lane >> 4;

    // bijective XCD swizzle: 1536 = 8 * 192; same-bh blocks on one XCD
    const int bid = blockIdx.x;
    const int lid = (bid & 7) * 192 + (bid >> 3);
    const int qt = lid & 15;            // 0..15
    const int bh = lid >> 4;            // 0..95
    const int b = bh / HEADS, h = bh % HEADS;

    const size_t base = (size_t)bh * SEQ * HD;
    const unsigned short* Qhb = Qh + base;
    const unsigned short* Qlb = Ql + base;
    const unsigned short* Khb = Kh + base;
    const unsigned short* Klb = Kl + base;
    const unsigned short* Vtb = Vt + base;      // [HD][SEQ]

    const int q0 = qt * 64 + wave * 16;

    // Q fragments (B-operand in swapped QK^T; same per-lane layout)
    short8 qh[2], ql[2];
    #pragma unroll
    for (int kk = 0; kk < 2; ++kk) {
        const size_t off = (size_t)(q0 + lr) * HD + kk * 32 + (lg << 3);
        qh[kk] = *reinterpret_cast<const short8*>(Qhb + off);
        ql[kk] = *reinterpret_cast<const short8*>(Qlb + off);
    }

    float m = -1.0e30f, l = 0.f;     // per-lane scalars: lane owns q-row lr
    f32x4 oacc[4];
    const f32x4 fzero = {0.f, 0.f, 0.f, 0.f};
    #pragma unroll
    for (int d = 0; d < 4; ++d) oacc[d] = fzero;

    for (int t = 0; t < SEQ / 64; ++t) {
        const int kbase = t * 64;

        __syncthreads();                 // all waves done reading previous tiles
        // burst-stage V^T, Kh, Kl (straight 16B copies)
        #pragma unroll
        for (int p = 0; p < 2; ++p) {
            int idx = (p << 8) + tid;
            int r = idx >> 3, c = (idx & 7) << 3;
            *reinterpret_cast<uint4*>(&Vs[r][c]) =
                *reinterpret_cast<const uint4*>(Vtb + (size_t)r * SEQ + kbase + c);
            *reinterpret_cast<uint4*>(&Ksh[r][c]) =
                *reinterpret_cast<const uint4*>(Khb + (size_t)(kbase + r) * HD + c);
            *reinterpret_cast<uint4*>(&Ksl[r][c]) =
                *reinterpret_cast<const uint4*>(Klb + (size_t)(kbase + r) * HD + c);
        }
        __syncthreads();

        // S^T = K Q^T: lane (lr,lg) gets q=lr, keys kbase + n*16 + lg*4 + j
        f32x4 s[4];
        #pragma unroll
        for (int n = 0; n < 4; ++n) s[n] = fzero;
        #pragma unroll
        for (int n = 0; n < 4; ++n) {
            #pragma unroll
            for (int kk = 0; kk < 2; ++kk) {
                const short8 kh = *reinterpret_cast<const short8*>(&Ksh[n * 16 + lr][kk * 32 + (lg << 3)]);
                const short8 kl = *reinterpret_cast<const short8*>(&Ksl[n * 16 + lr][kk * 32 + (lg << 3)]);
                s[n] = MFMA16(kh, qh[kk], s[n]);
                s[n] = MFMA16(kh, ql[kk], s[n]);
                s[n] = MFMA16(kl, qh[kk], s[n]);
            }
        }

        // row max: 16 in-lane values, then 2 cross-lg shuffles
        float t0 = fmaxf(fmaxf(s[0][0], s[0][1]), fmaxf(s[0][2], s[0][3]));
        float t1 = fmaxf(fmaxf(s[1][0], s[1][1]), fmaxf(s[1][2], s[1][3]));
        float t2 = fmaxf(fmaxf(s[2][0], s[2][1]), fmaxf(s[2][2], s[2][3]));
        float t3 = fmaxf(fmaxf(s[3][0], s[3][1]), fmaxf(s[3][2], s[3][3]));
        float tmax = fmaxf(fmaxf(t0, t1), fmaxf(t2, t3));
        tmax = fmaxf(tmax, __shfl_xor(tmax, 16));
        tmax = fmaxf(tmax, __shfl_xor(tmax, 32));

        const float mnew = fmaxf(m, tmax);
        const float corr = __expf(m - mnew);
        m = mnew;

        float psum = 0.f;
        #pragma unroll
        for (int n = 0; n < 4; ++n) {
            const float p0 = __expf(s[n][0] - mnew), p1 = __expf(s[n][1] - mnew);
            const float p2 = __expf(s[n][2] - mnew), p3 = __expf(s[n][3] - mnew);
            psum += (p0 + p1) + (p2 + p3);
            uint2 w = { (uint32_t)f2bf(p0) | ((uint32_t)f2bf(p1) << 16),
                        (uint32_t)f2bf(p2) | ((uint32_t)f2bf(p3) << 16) };
            *reinterpret_cast<uint2*>(&Plds[wave][lr][n * 16 + (lg << 2)]) = w;
        }
        psum += __shfl_xor(psum, 16);
        psum += __shfl_xor(psum, 32);
        l = l * corr + psum;

        // rescale O rows q' = lg*4+j (corr lives at lane lr=q', lg=0)
        #pragma unroll
        for (int j = 0; j < 4; ++j) {
            const float cj = __shfl(corr, (lg << 2) + j);
            oacc[0][j] *= cj; oacc[1][j] *= cj;
            oacc[2][j] *= cj; oacc[3][j] *= cj;
        }

        // O += P V  (A = P from per-wave LDS; B = V^T from LDS)
        #pragma unroll
        for (int kk = 0; kk < 2; ++kk) {
            const short8 ap = *reinterpret_cast<const short8*>(&Plds[wave][lr][kk * 32 + (lg << 3)]);
            #pragma unroll
            for (int d = 0; d < 4; ++d) {
                const short8 bv = *reinterpret_cast<const short8*>(&Vs[d * 16 + lr][kk * 32 + (lg << 3)]);
                oacc[d] = MFMA16(ap, bv, oacc[d]);
            }
        }
    }

    // epilogue: O / l / sqrt(768); l lives at lane lr=q', fetch via shfl
    const float rs = 0.036084391824351615f;  // 1/sqrt(768)
    #pragma unroll
    for (int j = 0; j < 4; ++j) {
        const float lj = __shfl(l, (lg << 2) + j);
        const float sc = rs / lj;
        const int q = q0 + (lg << 2) + j;
        #pragma unroll
        for (int d = 0; d < 4; ++d) {
            const float val = oacc[d][j] * sc;
            Ob[((size_t)b * SEQ + q) * EMB + h * HD + d * 16 + lr] = f2bf(val);
        }
    }
}

// ---------------------------------------------------------------------------
// Proj GEMM (r9-verified): Ob bf16 @ W_proj (fp32->bf16 RN) + b -> fp32 d_out.
// ---------------------------------------------------------------------------
__global__ __launch_bounds__(256, 2)
void gemm_proj(const unsigned short* __restrict__ A, const float* __restrict__ W,
               const float* __restrict__ bias, float* __restrict__ Out)
{
    __shared__ unsigned short As[128][40];
    __shared__ unsigned short Bs[128][40];

    const int tid  = threadIdx.x;
    const int wave = tid >> 6, lane = tid & 63;
    const int lr = lane & 15, lg = lane >> 4;
    const int wr = (wave >> 1) * 64, wc = (wave & 1) * 64;
    const int m0 = blockIdx.y * 128;
    const int c0 = blockIdx.x * 128;

    const f32x4 fzero = {0.f, 0.f, 0.f, 0.f};
    f32x4 acc[4][4];
    #pragma unroll
    for (int m = 0; m < 4; ++m)
        #pragma unroll
        for (int n = 0; n < 4; ++n) acc[m][n] = fzero;

    const int kgB = tid & 7, cgB = tid >> 3;

    for (int k0 = 0; k0 < EMB; k0 += 32) {
        #pragma unroll
        for (int p = 0; p < 2; ++p) {
            int idx = (p << 8) + tid;
            int row = idx >> 2, kc = (idx & 3) << 3;
            uint4 v = *reinterpret_cast<const uint4*>(A + (size_t)(m0 + row) * EMB + k0 + kc);
            *reinterpret_cast<uint4*>(&As[row][kc]) = v;
        }
        {
            f32x4 v[4];
            #pragma unroll
            for (int i = 0; i < 4; ++i)
                v[i] = *reinterpret_cast<const f32x4*>(
                    W + (size_t)(k0 + kgB * 4 + i) * EMB + c0 + cgB * 4);
            #pragma unroll
            for (int j = 0; j < 4; ++j) {
                uint2 w = { (uint32_t)f2bf(v[0][j]) | ((uint32_t)f2bf(v[1][j]) << 16),
                            (uint32_t)f2bf(v[2][j]) | ((uint32_t)f2bf(v[3][j]) << 16) };
                *reinterpret_cast<uint2*>(&Bs[cgB * 4 + j][kgB * 4]) = w;
            }
        }
        __syncthreads();

        short8 a[4], b[4];
        #pragma unroll
        for (int m = 0; m < 4; ++m)
            a[m] = *reinterpret_cast<const short8*>(&As[wr + m * 16 + lr][lg << 3]);
        #pragma unroll
        for (int n = 0; n < 4; ++n)
            b[n] = *reinterpret_cast<const short8*>(&Bs[wc + n * 16 + lr][lg << 3]);
        #pragma unroll
        for (int m = 0; m < 4; ++m)
            #pragma unroll
            for (int n = 0; n < 4; ++n)
                acc[m][n] = MFMA16(a[m], b[n], acc[m][n]);
        __syncthreads();
    }

    #pragma unroll
    for (int m = 0; m < 4; ++m) {
        #pragma unroll
        for (int n = 0; n < 4; ++n) {
            const int colg = c0 + wc + n * 16 + lr;
            const float bv = bias[colg];
            #pragma unroll
            for (int j = 0; j < 4; ++j) {
                const int rowg = m0 + wr + m * 16 + (lg << 2) + j;
                Out[(size_t)rowg * EMB + colg] = acc[m][n][j] + bv;   // fp32 out
            }
        }
    }
}

// ---------------------------------------------------------------------------
extern "C" void kernel_launch(void* const* d_in, const int* in_sizes, int n_in,
                              void* d_out, int out_size, void* d_ws, size_t ws_size,
                              hipStream_t stream)
{
    const float* x     = (const float*)d_in[0];
    const float* Wqkv  = (const float*)d_in[1];
    const float* bqkv  = (const float*)d_in[2];
    const float* Wproj = (const float*)d_in[3];
    const float* bproj = (const float*)d_in[4];
    float* out = (float*)d_out;    // reference output dtype = float32

    const size_t NQ = (size_t)BATCH * HEADS * SEQ * HD;  // 6291456
    unsigned short* Qh = (unsigned short*)d_ws;
    unsigned short* Ql = Qh + NQ;
    unsigned short* Kh = Ql + NQ;
    unsigned short* Kl = Kh + NQ;
    unsigned short* Vt = Kl + NQ;                        // [B,H,D,N] transposed
    unsigned short* Ob = Vt + NQ;                        // total 75.5 MB

    gemm_qkv<<<dim3(QKV_COLS / 128, M_ROWS / 128), 256, 0, stream>>>(
        x, Wqkv, bqkv, Qh, Ql, Kh, Kl, Vt);
    attn_fused<<<dim3(16 * BATCH * HEADS), 256, 0, stream>>>(Qh, Ql, Kh, Kl, Vt, Ob);
    gemm_proj<<<dim3(EMB / 128, M_ROWS / 128), 256, 0, stream>>>(
        Ob, Wproj, bproj, out);
}